// Round 20
// baseline (161.555 us; speedup 1.0000x reference)
//
#include <hip/hip_runtime.h>
#include <hip/hip_bf16.h>
#include <math.h>

// ---------------------------------------------------------------------------
// GCN forward, algebraically collapsed:
//   h1 = relu( dinv[d]*(sum_{e:dst=d} g[src_e] + g[d]) + b1 ),  g = (x@W1)*dinv
//   pooled = (1/N) * (sum_n w[n]*h1[n]) @ W2 + b2,
//       w[n] = dinv[n]*(wacc[n] + dinv[n]),  wacc[n] = sum_{e:src=n} dinv[dst_e]
//   out = sigmoid(pooled @ Wl + bl)
//
// g stored FP8 e4m3 (row = 64B = one cache line per edge gather; HW
// cvt_pk_f32_fp8 decode). GEMM: MFMA, A prefetched direct from global.
// Edges partitioned into 128-node buckets by dst AND src in ONE merged
// kernel. agg: ONE block per bucket; 32 quarter-waves; edges sorted by
// (dst&31, dst>>5, src>>14) into 128 segments/bucket -> within a segment the
// target row is CONSTANT, so each quarter-wave accumulates in REGISTERS and
// does ONE plain LDS write per segment (no RMW, no atomics, no zero-init).
// agg absorbs wacc via fixed-point int LDS atomics (ds_add_u32 native;
// float LDS atomicAdd is a CAS loop — r10: 65->678us).
// LESSON: splitting one bucket's edges across BLOCKS doubles HBM fetch
// (r12 rows, r14 cols).
// ---------------------------------------------------------------------------

#define F_IN 256
#define H 64
#define BSHIFT 7
#define BSZ 128
#define NBUCK_MAX 1024
#define P3_CH 8192
#define WSCALE 16777216.0f
#define WINV   (1.0f / 16777216.0f)

typedef __attribute__((ext_vector_type(8))) short bf16x8;
typedef __attribute__((ext_vector_type(4))) float f32x4;
typedef __attribute__((ext_vector_type(2))) float f32x2;
typedef unsigned char uchar;

__device__ __forceinline__ ushort f2bf(float f) {
    uint b = __float_as_uint(f);
    return (ushort)((b + 0x7FFFu + ((b >> 16) & 1u)) >> 16);   // RNE
}
__device__ __forceinline__ float bf2f(ushort u) {
    return __uint_as_float(((uint)u) << 16);
}
__device__ __forceinline__ uchar f2fp8(float f) {
    return (uchar)(__builtin_amdgcn_cvt_pk_fp8_f32(f, f, 0, false) & 0xff);
}
__device__ __forceinline__ float fp82f(uchar u) {
    f32x2 d = __builtin_amdgcn_cvt_pk_f32_fp8((uint)u, false);
    return d[0];
}

// ---- P1: dual bucket histogram (dst>>7 and src>>7) -------------------------
__global__ __launch_bounds__(256) void hist_kernel(const int* __restrict__ ei,
                                                   int* __restrict__ bcnt_d,
                                                   int* __restrict__ bcnt_s,
                                                   int E, int nbuck) {
    __shared__ int hd[NBUCK_MAX], hs[NBUCK_MAX];
    for (int i = threadIdx.x; i < NBUCK_MAX; i += 256) { hd[i] = 0; hs[i] = 0; }
    __syncthreads();
    int stride = gridDim.x * 256;
    for (int e = blockIdx.x * 256 + threadIdx.x; e < E; e += stride) {
        atomicAdd(&hd[ei[E + e] >> BSHIFT], 1);
        atomicAdd(&hs[ei[e] >> BSHIFT], 1);
    }
    __syncthreads();
    for (int b = threadIdx.x; b < nbuck; b += 256) {
        if (hd[b]) atomicAdd(&bcnt_d[b], hd[b]);
        if (hs[b]) atomicAdd(&bcnt_s[b], hs[b]);
    }
}

// ---- P2: scan bucket counts (block 0: dst, block 1: src) -------------------
__global__ __launch_bounds__(1024) void bscan_kernel(const int* __restrict__ bcnt_d,
                                                     const int* __restrict__ bcnt_s,
                                                     int* __restrict__ bbase_d,
                                                     int* __restrict__ bcur_d,
                                                     int* __restrict__ bbase_s,
                                                     int* __restrict__ bcur_s,
                                                     int nbuck, int E) {
    __shared__ int lds[1024];
    int t = threadIdx.x;
    const int* bcnt = blockIdx.x ? bcnt_s : bcnt_d;
    int* bbase = blockIdx.x ? bbase_s : bbase_d;
    int* bcur  = blockIdx.x ? bcur_s  : bcur_d;
    int v = (t < nbuck) ? bcnt[t] : 0;
    lds[t] = v;
    __syncthreads();
    #pragma unroll
    for (int off = 1; off < 1024; off <<= 1) {
        int u = (t >= off) ? lds[t - off] : 0;
        __syncthreads();
        lds[t] += u;
        __syncthreads();
    }
    if (t < nbuck) { bbase[t] = lds[t] - v; bcur[t] = lds[t] - v; }
    if (t == 0) bbase[nbuck] = E;
}

// ---- P3: merged dual partition (dst then src) — chunk held in registers ----
__global__ __launch_bounds__(512) void part2_kernel(const int* __restrict__ ei,
                                                    int* __restrict__ bcur_d,
                                                    int* __restrict__ bcur_s,
                                                    int* __restrict__ recs_d,
                                                    int* __restrict__ srecs,
                                                    int E) {
    __shared__ int hist[NBUCK_MAX], segb[NBUCK_MAX], blkb[NBUCK_MAX], ctr[NBUCK_MAX];
    __shared__ int scanbuf[512];
    __shared__ int stage[P3_CH];
    __shared__ ushort sbuck[P3_CH];
    int t = threadIdx.x;
    int base = blockIdx.x * P3_CH;
    int cnt = E - base; if (cnt > P3_CH) cnt = P3_CH;
    int s_[16], d_[16];
    #pragma unroll
    for (int i = 0; i < 16; ++i) {
        int idx = t + i * 512;
        if (idx < cnt) { s_[i] = ei[base + idx]; d_[i] = ei[E + base + idx]; }
        else           { s_[i] = -1;             d_[i] = -1; }
    }
    #pragma unroll
    for (int phase = 0; phase < 2; ++phase) {
        int* bcur = phase ? bcur_s : bcur_d;
        int* recs = phase ? srecs  : recs_d;
        for (int i = t; i < NBUCK_MAX; i += 512) { hist[i] = 0; ctr[i] = 0; }
        __syncthreads();
        #pragma unroll
        for (int i = 0; i < 16; ++i) {
            int key = phase ? s_[i] : d_[i];
            if (key >= 0) atomicAdd(&hist[key >> BSHIFT], 1);
        }
        __syncthreads();
        int v0 = hist[2 * t], v1 = hist[2 * t + 1];
        int s = v0 + v1;
        scanbuf[t] = s;
        __syncthreads();
        #pragma unroll
        for (int off = 1; off < 512; off <<= 1) {
            int u = (t >= off) ? scanbuf[t - off] : 0;
            __syncthreads();
            scanbuf[t] += u;
            __syncthreads();
        }
        int excl = scanbuf[t] - s;
        segb[2 * t] = excl;
        segb[2 * t + 1] = excl + v0;
        if (v0) blkb[2 * t]     = atomicAdd(&bcur[2 * t],     v0);
        if (v1) blkb[2 * t + 1] = atomicAdd(&bcur[2 * t + 1], v1);
        __syncthreads();
        #pragma unroll
        for (int i = 0; i < 16; ++i) {
            int key   = phase ? s_[i] : d_[i];
            int other = phase ? d_[i] : s_[i];
            if (key >= 0) {
                int bb = key >> BSHIFT;
                int r = atomicAdd(&ctr[bb], 1);
                int pos = segb[bb] + r;
                stage[pos] = (other << BSHIFT) | (key & (BSZ - 1));
                sbuck[pos] = (ushort)bb;
            }
        }
        __syncthreads();
        for (int i = t; i < cnt; i += 512) {
            int bb = sbuck[i];
            recs[blkb[bb] + (i - segb[bb])] = stage[i];
        }
        __syncthreads();
    }
}

// ---- P4: per-dst-bucket counting sort by (dst&31, dst>>5, src>>14) ---------
__global__ __launch_bounds__(256) void build_kernel(const int* __restrict__ recs,
                                                    const int* __restrict__ bbase,
                                                    float* __restrict__ dinv,
                                                    int* __restrict__ sedge,
                                                    int* __restrict__ qbase,
                                                    int N, int NSB) {
    __shared__ int cnt[BSZ];
    __shared__ int bh[NBUCK_MAX];
    __shared__ int bbl[NBUCK_MAX];
    __shared__ int bctr[NBUCK_MAX];
    __shared__ int scanbuf[256];
    int b = blockIdx.x, t = threadIdx.x;
    int e0 = bbase[b], e1 = bbase[b + 1];
    if (t < BSZ) cnt[t] = 0;
    for (int i = t; i < NBUCK_MAX; i += 256) { bh[i] = 0; bctr[i] = 0; }
    __syncthreads();
    // seg = (dl&31)*4 + (dl>>5); bin = seg*NSB + (src>>14)   [src = p>>7]
    for (int i = e0 + t; i < e1; i += 256) {
        int p = recs[i];
        int dl = p & (BSZ - 1);
        atomicAdd(&cnt[dl], 1);
        int seg = ((p & 31) << 2) | ((p >> 5) & 3);
        atomicAdd(&bh[seg * NSB + ((unsigned)p >> 21)], 1);
    }
    __syncthreads();
    int b0 = bh[4 * t], b1 = bh[4 * t + 1], b2 = bh[4 * t + 2], b3 = bh[4 * t + 3];
    int s = b0 + b1 + b2 + b3;
    scanbuf[t] = s;
    __syncthreads();
    #pragma unroll
    for (int off = 1; off < 256; off <<= 1) {
        int u = (t >= off) ? scanbuf[t - off] : 0;
        __syncthreads();
        scanbuf[t] += u;
        __syncthreads();
    }
    int excl = scanbuf[t] - s;
    bbl[4 * t] = excl;
    bbl[4 * t + 1] = excl + b0;
    bbl[4 * t + 2] = excl + b0 + b1;
    bbl[4 * t + 3] = excl + b0 + b1 + b2;
    __syncthreads();
    if (t < BSZ) qbase[b * BSZ + t] = bbl[t * NSB];
    if (t < BSZ) {
        int n = (b << BSHIFT) + t;
        if (n < N) dinv[n] = rsqrtf(1.0f + (float)cnt[t]);
    }
    __syncthreads();
    for (int i = e0 + t; i < e1; i += 256) {
        int p = recs[i];
        int seg = ((p & 31) << 2) | ((p >> 5) & 3);
        int bin = seg * NSB + ((unsigned)p >> 21);
        int pos = atomicAdd(&bctr[bin], 1);
        sedge[e0 + bbl[bin] + pos] = p;
    }
}

// ---- W1 -> W1^T bf16 (B^T form for MFMA) -----------------------------------
__global__ __launch_bounds__(256) void w1t_kernel(const float* __restrict__ W1,
                                                  ushort* __restrict__ W1t) {
    int idx = blockIdx.x * 256 + threadIdx.x;
    int n = idx >> 8;
    int k = idx & 255;
    W1t[n * 256 + k] = f2bf(W1[k * 64 + n]);
}

// ---- K4: MFMA GEMM  g = (x @ W1) * dinv  (fp8 out, A prefetched) -----------
__global__ __launch_bounds__(256) void gemm_mfma(const float* __restrict__ x,
                                                 const ushort* __restrict__ W1t,
                                                 const float* __restrict__ dinv,
                                                 uchar* __restrict__ gb, int M) {
    __shared__ ushort Bs[64 * 256];   // 32 KB, row-major [n][k], swizzled
    int t = threadIdx.x;
    int rowbase = blockIdx.x * 64;

    #pragma unroll
    for (int i = 0; i < 8; ++i) {
        int idx = t + i * 256;
        int r   = idx >> 5;
        int c8  = idx & 31;
        uint4 v = *reinterpret_cast<const uint4*>(&W1t[r * 256 + c8 * 8]);
        int byteoff = r * 512 + ((c8 * 16) ^ ((r & 15) << 4));
        *reinterpret_cast<uint4*>((char*)Bs + byteoff) = v;
    }

    int lane = t & 63;
    int w    = t >> 6;
    int lsw  = (lane & 15) << 4;
    int arow = rowbase + w * 16 + (lane & 15);
    bool avalid = arow < M;
    const float* xp = x + (size_t)arow * F_IN;

    float4 xv[16];
    #pragma unroll
    for (int c = 0; c < 8; ++c) {
        int k0 = c * 32 + ((lane >> 4) << 3);
        if (avalid) {
            xv[2 * c]     = *reinterpret_cast<const float4*>(xp + k0);
            xv[2 * c + 1] = *reinterpret_cast<const float4*>(xp + k0 + 4);
        } else {
            xv[2 * c] = make_float4(0.f, 0.f, 0.f, 0.f);
            xv[2 * c + 1] = make_float4(0.f, 0.f, 0.f, 0.f);
        }
    }
    __syncthreads();

    f32x4 acc0 = {0.f, 0.f, 0.f, 0.f}, acc1 = acc0, acc2 = acc0, acc3 = acc0;
    #pragma unroll
    for (int c = 0; c < 8; ++c) {
        float4 v0 = xv[2 * c], v1 = xv[2 * c + 1];
        bf16x8 a;
        a[0] = (short)f2bf(v0.x); a[1] = (short)f2bf(v0.y);
        a[2] = (short)f2bf(v0.z); a[3] = (short)f2bf(v0.w);
        a[4] = (short)f2bf(v1.x); a[5] = (short)f2bf(v1.y);
        a[6] = (short)f2bf(v1.z); a[7] = (short)f2bf(v1.w);
        int kb = c * 64 + ((lane >> 4) << 4);
        int kbs = kb ^ lsw;
        bf16x8 bf0 = *reinterpret_cast<const bf16x8*>((char*)Bs + ( 0 + (lane & 15)) * 512 + kbs);
        bf16x8 bf1 = *reinterpret_cast<const bf16x8*>((char*)Bs + (16 + (lane & 15)) * 512 + kbs);
        bf16x8 bf2 = *reinterpret_cast<const bf16x8*>((char*)Bs + (32 + (lane & 15)) * 512 + kbs);
        bf16x8 bf3 = *reinterpret_cast<const bf16x8*>((char*)Bs + (48 + (lane & 15)) * 512 + kbs);
        acc0 = __builtin_amdgcn_mfma_f32_16x16x32_bf16(a, bf0, acc0, 0, 0, 0);
        acc1 = __builtin_amdgcn_mfma_f32_16x16x32_bf16(a, bf1, acc1, 0, 0, 0);
        acc2 = __builtin_amdgcn_mfma_f32_16x16x32_bf16(a, bf2, acc2, 0, 0, 0);
        acc3 = __builtin_amdgcn_mfma_f32_16x16x32_bf16(a, bf3, acc3, 0, 0, 0);
    }
    #pragma unroll
    for (int reg = 0; reg < 4; ++reg) {
        int grow = rowbase + w * 16 + ((lane >> 4) << 2) + reg;
        if (grow < M) {
            float dv = dinv[grow];
            uchar* gp = &gb[(size_t)grow * H + (lane & 15)];
            gp[ 0] = f2fp8(acc0[reg] * dv);
            gp[16] = f2fp8(acc1[reg] * dv);
            gp[32] = f2fp8(acc2[reg] * dv);
            gp[48] = f2fp8(acc3[reg] * dv);
        }
    }
}

// ---- K6: agg — register accumulation, one LDS write per segment ------------
// Quarter-wave hw processes segments seg=hw*4+k (k=0..3); within a segment
// the target row dl = hw + 32k is constant -> accumulate in registers,
// store acc[dl][c0..c0+3] once. No LDS RMW, no zero-init (full coverage).
__global__ __launch_bounds__(512) void agg_kernel(const uchar* __restrict__ gb,
                                                  const int* __restrict__ bbase,
                                                  const int* __restrict__ bbase_s,
                                                  const int* __restrict__ qbase,
                                                  const int* __restrict__ sedge,
                                                  const int* __restrict__ srecs,
                                                  const float* __restrict__ dinv,
                                                  const float* __restrict__ b1,
                                                  float* __restrict__ svec, int N) {
    __shared__ float acc[BSZ][H];            // 32 KB (write-once per chunk)
    __shared__ int   wli[BSZ];               // fixed-point 2^24
    __shared__ float red[8][64];
    int t = threadIdx.x;
    int lane = t & 63;
    int w = t >> 6;                          // wave 0..7
    int qq = lane >> 4;                      // quarter-wave 0..3
    int cl4 = lane & 15;                     // covers cols [cl4*4, cl4*4+4)
    int b = blockIdx.x;
    if (t < BSZ) wli[t] = 0;
    __syncthreads();
    // ---- wacc phase: wli[src&127] += round(dinv[dst]*2^24) (native ds_add)
    {
        int e0s = bbase_s[b], e1s = bbase_s[b + 1];
        for (int i = e0s + t; i < e1s; i += 512) {
            int p = srecs[i];                          // (dst<<7)|(src&127)
            int fx = (int)(dinv[(unsigned)p >> BSHIFT] * WSCALE + 0.5f);
            atomicAdd(&wli[p & (BSZ - 1)], fx);
        }
    }
    // ---- main gather phase: per-segment register accumulation
    int e0 = bbase[b];
    int m  = bbase[b + 1] - e0;
    int hw = (w << 2) | qq;                  // 0..31
    const int* sp = sedge + e0;
    int c0 = cl4 << 2;
    #pragma unroll
    for (int k = 0; k < 4; ++k) {
        int seg = hw * 4 + k;
        int qs = qbase[b * BSZ + seg];
        int qe = (seg < BSZ - 1) ? qbase[b * BSZ + seg + 1] : m;
        float4 r0 = make_float4(0.f, 0.f, 0.f, 0.f);
        float4 r1 = r0, r2 = r0, r3 = r0;
        int j = qs;
        for (; j + 3 < qe; j += 4) {
            int p0 = sp[j], p1 = sp[j + 1], p2 = sp[j + 2], p3 = sp[j + 3];
            uint u0 = *reinterpret_cast<const uint*>(gb + (((unsigned)p0 >> BSHIFT) << 6) + c0);
            uint u1 = *reinterpret_cast<const uint*>(gb + (((unsigned)p1 >> BSHIFT) << 6) + c0);
            uint u2 = *reinterpret_cast<const uint*>(gb + (((unsigned)p2 >> BSHIFT) << 6) + c0);
            uint u3 = *reinterpret_cast<const uint*>(gb + (((unsigned)p3 >> BSHIFT) << 6) + c0);
            f32x2 l0 = __builtin_amdgcn_cvt_pk_f32_fp8(u0, false);
            f32x2 h0 = __builtin_amdgcn_cvt_pk_f32_fp8(u0, true);
            r0.x += l0[0]; r0.y += l0[1]; r0.z += h0[0]; r0.w += h0[1];
            f32x2 l1 = __builtin_amdgcn_cvt_pk_f32_fp8(u1, false);
            f32x2 h1 = __builtin_amdgcn_cvt_pk_f32_fp8(u1, true);
            r1.x += l1[0]; r1.y += l1[1]; r1.z += h1[0]; r1.w += h1[1];
            f32x2 l2 = __builtin_amdgcn_cvt_pk_f32_fp8(u2, false);
            f32x2 h2 = __builtin_amdgcn_cvt_pk_f32_fp8(u2, true);
            r2.x += l2[0]; r2.y += l2[1]; r2.z += h2[0]; r2.w += h2[1];
            f32x2 l3 = __builtin_amdgcn_cvt_pk_f32_fp8(u3, false);
            f32x2 h3 = __builtin_amdgcn_cvt_pk_f32_fp8(u3, true);
            r3.x += l3[0]; r3.y += l3[1]; r3.z += h3[0]; r3.w += h3[1];
        }
        for (; j < qe; ++j) {
            int p = sp[j];
            uint u = *reinterpret_cast<const uint*>(gb + (((unsigned)p >> BSHIFT) << 6) + c0);
            f32x2 lo = __builtin_amdgcn_cvt_pk_f32_fp8(u, false);
            f32x2 hi = __builtin_amdgcn_cvt_pk_f32_fp8(u, true);
            r0.x += lo[0]; r0.y += lo[1]; r0.z += hi[0]; r0.w += hi[1];
        }
        float4 s;
        s.x = (r0.x + r1.x) + (r2.x + r3.x);
        s.y = (r0.y + r1.y) + (r2.y + r3.y);
        s.z = (r0.z + r1.z) + (r2.z + r3.z);
        s.w = (r0.w + r1.w) + (r2.w + r3.w);
        int dl = hw + (k << 5);
        *reinterpret_cast<float4*>(&acc[dl][c0]) = s;
    }
    __syncthreads();
    // ---- finalize
    float bb = b1[lane];
    float racc = 0.f;
    #pragma unroll
    for (int r = 0; r < 16; ++r) {
        int dl = r * 8 + w;
        int n = (b << BSHIFT) + dl;
        if (n < N) {
            float dv = dinv[n];
            float a = acc[dl][lane] + fp82f(gb[(size_t)n * H + lane]);
            float h1 = fmaxf(dv * a + bb, 0.f);
            racc += (dv * ((float)wli[dl] * WINV + dv)) * h1;
        }
    }
    red[w][lane] = racc;
    __syncthreads();
    if (w == 0) {
        float vv = 0.f;
        #pragma unroll
        for (int k = 0; k < 8; ++k) vv += red[k][lane];
        atomicAdd(&svec[lane], vv);
    }
}

// ---- K7: final tiny head ---------------------------------------------------
__global__ void final_kernel(const float* __restrict__ svec,
                             const float* __restrict__ W2, const float* __restrict__ b2,
                             const float* __restrict__ Wl, const float* __restrict__ bl,
                             float* __restrict__ out, float invN) {
    __shared__ float pooled[64];
    __shared__ float sv[64];
    int t = threadIdx.x;
    sv[t] = svec[t];
    __syncthreads();
    float acc = 0.f;
    for (int k = 0; k < 64; ++k) acc += sv[k] * W2[k * 64 + t];
    pooled[t] = acc * invN + b2[t];
    __syncthreads();
    if (t < 10) {
        float a = 0.f;
        for (int j = 0; j < 64; ++j) a += pooled[j] * Wl[j * 10 + t];
        a += bl[t];
        out[t] = 1.f / (1.f + expf(-a));
    }
}

// ---------------------------------------------------------------------------
extern "C" void kernel_launch(void* const* d_in, const int* in_sizes, int n_in,
                              void* d_out, int out_size, void* d_ws, size_t ws_size,
                              hipStream_t stream) {
    const float* x   = (const float*)d_in[0];
    const int*   ei  = (const int*)d_in[1];
    const float* W1  = (const float*)d_in[2];
    const float* b1  = (const float*)d_in[3];
    const float* W2  = (const float*)d_in[4];
    const float* b2  = (const float*)d_in[5];
    const float* Wl  = (const float*)d_in[6];
    const float* bl  = (const float*)d_in[7];
    float* out = (float*)d_out;

    const int N = in_sizes[0] / F_IN;
    const int E = in_sizes[1] / 2;
    const int nbuck = (N + BSZ - 1) >> BSHIFT;       // 782 for N=100000
    const int NSB   = (N + 16383) >> 14;             // 7 src bins (128*NSB <= 1024)

    char* ws = (char*)d_ws;
    size_t off = 0;
    auto carve = [&](size_t bytes) -> char* {
        char* p = ws + off;
        off = (off + bytes + 255) & ~(size_t)255;
        return p;
    };
    int*   bcnt2    = (int*)  carve((size_t)2 * NBUCK_MAX * 4);  // [dst | src]
    int*   bcnt_d   = bcnt2;
    int*   bcnt_s   = bcnt2 + NBUCK_MAX;
    int*   bbase_d  = (int*)  carve((size_t)(NBUCK_MAX + 1) * 4);
    int*   bcur_d   = (int*)  carve((size_t)NBUCK_MAX * 4);
    int*   bbase_s  = (int*)  carve((size_t)(NBUCK_MAX + 1) * 4);
    int*   bcur_s   = (int*)  carve((size_t)NBUCK_MAX * 4);
    int*   qbase    = (int*)  carve((size_t)nbuck * BSZ * 4);
    float* dinv     = (float*)carve((size_t)N * 4);
    float* svec     = (float*)carve(64 * 4);
    ushort* W1t     = (ushort*)carve((size_t)64 * 256 * 2);
    int*   sedge    = (int*)  carve((size_t)E * 4);
    int*   srecs    = (int*)  carve((size_t)E * 4);
    // overlay: recs_d (E*4) reused as gb (N*64*1) after build
    size_t ovl = (size_t)E * 4;
    size_t gsz = (size_t)N * H;
    char*  ovlp     = carve(ovl > gsz ? ovl : gsz);
    int*   recs_d   = (int*)ovlp;
    uchar* gb       = (uchar*)ovlp;
    (void)ws_size; (void)n_in; (void)out_size;

    hipMemsetAsync(bcnt2, 0, (size_t)2 * NBUCK_MAX * 4, stream);
    hipMemsetAsync(svec, 0, 64 * 4, stream);

    w1t_kernel<<<64, 256, 0, stream>>>(W1, W1t);
    hist_kernel<<<120, 256, 0, stream>>>(ei, bcnt_d, bcnt_s, E, nbuck);
    bscan_kernel<<<2, 1024, 0, stream>>>(bcnt_d, bcnt_s, bbase_d, bcur_d, bbase_s, bcur_s, nbuck, E);
    int gridP3 = (E + P3_CH - 1) / P3_CH;
    part2_kernel<<<gridP3, 512, 0, stream>>>(ei, bcur_d, bcur_s, recs_d, srecs, E);
    build_kernel<<<nbuck, 256, 0, stream>>>(recs_d, bbase_d, dinv, sedge, qbase, N, NSB);

    int gridM = (N + 63) / 64;
    gemm_mfma<<<gridM, 256, 0, stream>>>(x, W1t, dinv, gb, N);

    agg_kernel<<<nbuck, 512, 0, stream>>>(gb, bbase_d, bbase_s, qbase, sedge, srecs,
                                          dinv, b1, svec, N);

    final_kernel<<<1, 64, 0, stream>>>(svec, W2, b2, Wl, bl, out, 1.0f / (float)N);
}

// Round 21
// 159.032 us; speedup vs baseline: 1.0159x; 1.0159x over previous
//
#include <hip/hip_runtime.h>
#include <hip/hip_bf16.h>
#include <math.h>

// ---------------------------------------------------------------------------
// GCN forward, algebraically collapsed:
//   h1 = relu( dinv[d]*(sum_{e:dst=d} g[src_e] + g[d]) + b1 ),  g = (x@W1)*dinv
//   pooled = (1/N) * (sum_n w[n]*h1[n]) @ W2 + b2,
//       w[n] = dinv[n]*(wacc[n] + dinv[n]),  wacc[n] = sum_{e:src=n} dinv[dst_e]
//   out = sigmoid(pooled @ Wl + bl)
//
// g stored FP8 e4m3 (row = 64B = one cache line per edge gather; HW
// cvt_pk_f32_fp8 decode). GEMM: MFMA, A prefetched direct from global.
// Edges partitioned into 128-node buckets by dst AND src in ONE merged
// kernel. agg: ONE block per bucket; 32 quarter-waves, qw hw owns rows
// dl&31==hw, walks its (dst&31, src>>12)-sorted segment; lane covers 4 cols
// (uint gather = 4 fp8, float4 LDS RMW) -> 4 edges per wave instruction.
// agg absorbs wacc via FIXED-POINT int LDS atomics (ds_add_u32 is native;
// float LDS atomicAdd is a CAS loop — r10: 65->678us).
// LESSONS: splitting one bucket's edges across BLOCKS doubles HBM fetch
// (r12 rows, r14 cols). agg is random-gather-bound (~57us): reg-accum (r20),
// occupancy (r12), and ILP (r14) variants all neutral or worse — this
// configuration is the measured floor (159.8us total).
// ---------------------------------------------------------------------------

#define F_IN 256
#define H 64
#define BSHIFT 7
#define BSZ 128
#define NBUCK_MAX 1024
#define P3_CH 8192
#define WSCALE 16777216.0f
#define WINV   (1.0f / 16777216.0f)

typedef __attribute__((ext_vector_type(8))) short bf16x8;
typedef __attribute__((ext_vector_type(4))) float f32x4;
typedef __attribute__((ext_vector_type(2))) float f32x2;
typedef unsigned char uchar;

__device__ __forceinline__ ushort f2bf(float f) {
    uint b = __float_as_uint(f);
    return (ushort)((b + 0x7FFFu + ((b >> 16) & 1u)) >> 16);   // RNE
}
__device__ __forceinline__ float bf2f(ushort u) {
    return __uint_as_float(((uint)u) << 16);
}
__device__ __forceinline__ uchar f2fp8(float f) {
    return (uchar)(__builtin_amdgcn_cvt_pk_fp8_f32(f, f, 0, false) & 0xff);
}
__device__ __forceinline__ float fp82f(uchar u) {
    f32x2 d = __builtin_amdgcn_cvt_pk_f32_fp8((uint)u, false);
    return d[0];
}

// ---- P1: dual bucket histogram (dst>>7 and src>>7) -------------------------
__global__ __launch_bounds__(256) void hist_kernel(const int* __restrict__ ei,
                                                   int* __restrict__ bcnt_d,
                                                   int* __restrict__ bcnt_s,
                                                   int E, int nbuck) {
    __shared__ int hd[NBUCK_MAX], hs[NBUCK_MAX];
    for (int i = threadIdx.x; i < NBUCK_MAX; i += 256) { hd[i] = 0; hs[i] = 0; }
    __syncthreads();
    int stride = gridDim.x * 256;
    for (int e = blockIdx.x * 256 + threadIdx.x; e < E; e += stride) {
        atomicAdd(&hd[ei[E + e] >> BSHIFT], 1);
        atomicAdd(&hs[ei[e] >> BSHIFT], 1);
    }
    __syncthreads();
    for (int b = threadIdx.x; b < nbuck; b += 256) {
        if (hd[b]) atomicAdd(&bcnt_d[b], hd[b]);
        if (hs[b]) atomicAdd(&bcnt_s[b], hs[b]);
    }
}

// ---- P2: scan bucket counts (block 0: dst, block 1: src) -------------------
__global__ __launch_bounds__(1024) void bscan_kernel(const int* __restrict__ bcnt_d,
                                                     const int* __restrict__ bcnt_s,
                                                     int* __restrict__ bbase_d,
                                                     int* __restrict__ bcur_d,
                                                     int* __restrict__ bbase_s,
                                                     int* __restrict__ bcur_s,
                                                     int nbuck, int E) {
    __shared__ int lds[1024];
    int t = threadIdx.x;
    const int* bcnt = blockIdx.x ? bcnt_s : bcnt_d;
    int* bbase = blockIdx.x ? bbase_s : bbase_d;
    int* bcur  = blockIdx.x ? bcur_s  : bcur_d;
    int v = (t < nbuck) ? bcnt[t] : 0;
    lds[t] = v;
    __syncthreads();
    #pragma unroll
    for (int off = 1; off < 1024; off <<= 1) {
        int u = (t >= off) ? lds[t - off] : 0;
        __syncthreads();
        lds[t] += u;
        __syncthreads();
    }
    if (t < nbuck) { bbase[t] = lds[t] - v; bcur[t] = lds[t] - v; }
    if (t == 0) bbase[nbuck] = E;
}

// ---- P3: merged dual partition (dst then src) — chunk held in registers ----
__global__ __launch_bounds__(512) void part2_kernel(const int* __restrict__ ei,
                                                    int* __restrict__ bcur_d,
                                                    int* __restrict__ bcur_s,
                                                    int* __restrict__ recs_d,
                                                    int* __restrict__ srecs,
                                                    int E) {
    __shared__ int hist[NBUCK_MAX], segb[NBUCK_MAX], blkb[NBUCK_MAX], ctr[NBUCK_MAX];
    __shared__ int scanbuf[512];
    __shared__ int stage[P3_CH];
    __shared__ ushort sbuck[P3_CH];
    int t = threadIdx.x;
    int base = blockIdx.x * P3_CH;
    int cnt = E - base; if (cnt > P3_CH) cnt = P3_CH;
    int s_[16], d_[16];
    #pragma unroll
    for (int i = 0; i < 16; ++i) {
        int idx = t + i * 512;
        if (idx < cnt) { s_[i] = ei[base + idx]; d_[i] = ei[E + base + idx]; }
        else           { s_[i] = -1;             d_[i] = -1; }
    }
    #pragma unroll
    for (int phase = 0; phase < 2; ++phase) {
        int* bcur = phase ? bcur_s : bcur_d;
        int* recs = phase ? srecs  : recs_d;
        for (int i = t; i < NBUCK_MAX; i += 512) { hist[i] = 0; ctr[i] = 0; }
        __syncthreads();
        #pragma unroll
        for (int i = 0; i < 16; ++i) {
            int key = phase ? s_[i] : d_[i];
            if (key >= 0) atomicAdd(&hist[key >> BSHIFT], 1);
        }
        __syncthreads();
        int v0 = hist[2 * t], v1 = hist[2 * t + 1];
        int s = v0 + v1;
        scanbuf[t] = s;
        __syncthreads();
        #pragma unroll
        for (int off = 1; off < 512; off <<= 1) {
            int u = (t >= off) ? scanbuf[t - off] : 0;
            __syncthreads();
            scanbuf[t] += u;
            __syncthreads();
        }
        int excl = scanbuf[t] - s;
        segb[2 * t] = excl;
        segb[2 * t + 1] = excl + v0;
        if (v0) blkb[2 * t]     = atomicAdd(&bcur[2 * t],     v0);
        if (v1) blkb[2 * t + 1] = atomicAdd(&bcur[2 * t + 1], v1);
        __syncthreads();
        #pragma unroll
        for (int i = 0; i < 16; ++i) {
            int key   = phase ? s_[i] : d_[i];
            int other = phase ? d_[i] : s_[i];
            if (key >= 0) {
                int bb = key >> BSHIFT;
                int r = atomicAdd(&ctr[bb], 1);
                int pos = segb[bb] + r;
                stage[pos] = (other << BSHIFT) | (key & (BSZ - 1));
                sbuck[pos] = (ushort)bb;
            }
        }
        __syncthreads();
        for (int i = t; i < cnt; i += 512) {
            int bb = sbuck[i];
            recs[blkb[bb] + (i - segb[bb])] = stage[i];
        }
        __syncthreads();
    }
}

// ---- P4: per-dst-bucket counting sort by (dst&31, src>>12) + dinv ----------
__global__ __launch_bounds__(256) void build_kernel(const int* __restrict__ recs,
                                                    const int* __restrict__ bbase,
                                                    float* __restrict__ dinv,
                                                    int* __restrict__ sedge,
                                                    int* __restrict__ qbase,
                                                    int N, int NSB) {
    __shared__ int cnt[BSZ];
    __shared__ int bh[NBUCK_MAX];
    __shared__ int bbl[NBUCK_MAX];
    __shared__ int bctr[NBUCK_MAX];
    __shared__ int scanbuf[256];
    int b = blockIdx.x, t = threadIdx.x;
    int e0 = bbase[b], e1 = bbase[b + 1];
    if (t < BSZ) cnt[t] = 0;
    for (int i = t; i < NBUCK_MAX; i += 256) { bh[i] = 0; bctr[i] = 0; }
    __syncthreads();
    for (int i = e0 + t; i < e1; i += 256) {
        int p = recs[i];
        int dl = p & (BSZ - 1);
        atomicAdd(&cnt[dl], 1);
        atomicAdd(&bh[(p & 31) * NSB + ((unsigned)p >> 19)], 1);  // (dst&31, src>>12)
    }
    __syncthreads();
    int b0 = bh[4 * t], b1 = bh[4 * t + 1], b2 = bh[4 * t + 2], b3 = bh[4 * t + 3];
    int s = b0 + b1 + b2 + b3;
    scanbuf[t] = s;
    __syncthreads();
    #pragma unroll
    for (int off = 1; off < 256; off <<= 1) {
        int u = (t >= off) ? scanbuf[t - off] : 0;
        __syncthreads();
        scanbuf[t] += u;
        __syncthreads();
    }
    int excl = scanbuf[t] - s;
    bbl[4 * t] = excl;
    bbl[4 * t + 1] = excl + b0;
    bbl[4 * t + 2] = excl + b0 + b1;
    bbl[4 * t + 3] = excl + b0 + b1 + b2;
    __syncthreads();
    if (t < 32) qbase[b * 32 + t] = bbl[t * NSB];
    if (t < BSZ) {
        int n = (b << BSHIFT) + t;
        if (n < N) dinv[n] = rsqrtf(1.0f + (float)cnt[t]);
    }
    __syncthreads();
    for (int i = e0 + t; i < e1; i += 256) {
        int p = recs[i];
        int bin = (p & 31) * NSB + ((unsigned)p >> 19);
        int pos = atomicAdd(&bctr[bin], 1);
        sedge[e0 + bbl[bin] + pos] = p;
    }
}

// ---- W1 -> W1^T bf16 (B^T form for MFMA) -----------------------------------
__global__ __launch_bounds__(256) void w1t_kernel(const float* __restrict__ W1,
                                                  ushort* __restrict__ W1t) {
    int idx = blockIdx.x * 256 + threadIdx.x;
    int n = idx >> 8;
    int k = idx & 255;
    W1t[n * 256 + k] = f2bf(W1[k * 64 + n]);
}

// ---- K4: MFMA GEMM  g = (x @ W1) * dinv  (fp8 out, A prefetched) -----------
__global__ __launch_bounds__(256) void gemm_mfma(const float* __restrict__ x,
                                                 const ushort* __restrict__ W1t,
                                                 const float* __restrict__ dinv,
                                                 uchar* __restrict__ gb, int M) {
    __shared__ ushort Bs[64 * 256];   // 32 KB, row-major [n][k], swizzled
    int t = threadIdx.x;
    int rowbase = blockIdx.x * 64;

    #pragma unroll
    for (int i = 0; i < 8; ++i) {
        int idx = t + i * 256;
        int r   = idx >> 5;
        int c8  = idx & 31;
        uint4 v = *reinterpret_cast<const uint4*>(&W1t[r * 256 + c8 * 8]);
        int byteoff = r * 512 + ((c8 * 16) ^ ((r & 15) << 4));
        *reinterpret_cast<uint4*>((char*)Bs + byteoff) = v;
    }

    int lane = t & 63;
    int w    = t >> 6;
    int lsw  = (lane & 15) << 4;
    int arow = rowbase + w * 16 + (lane & 15);
    bool avalid = arow < M;
    const float* xp = x + (size_t)arow * F_IN;

    float4 xv[16];
    #pragma unroll
    for (int c = 0; c < 8; ++c) {
        int k0 = c * 32 + ((lane >> 4) << 3);
        if (avalid) {
            xv[2 * c]     = *reinterpret_cast<const float4*>(xp + k0);
            xv[2 * c + 1] = *reinterpret_cast<const float4*>(xp + k0 + 4);
        } else {
            xv[2 * c] = make_float4(0.f, 0.f, 0.f, 0.f);
            xv[2 * c + 1] = make_float4(0.f, 0.f, 0.f, 0.f);
        }
    }
    __syncthreads();

    f32x4 acc0 = {0.f, 0.f, 0.f, 0.f}, acc1 = acc0, acc2 = acc0, acc3 = acc0;
    #pragma unroll
    for (int c = 0; c < 8; ++c) {
        float4 v0 = xv[2 * c], v1 = xv[2 * c + 1];
        bf16x8 a;
        a[0] = (short)f2bf(v0.x); a[1] = (short)f2bf(v0.y);
        a[2] = (short)f2bf(v0.z); a[3] = (short)f2bf(v0.w);
        a[4] = (short)f2bf(v1.x); a[5] = (short)f2bf(v1.y);
        a[6] = (short)f2bf(v1.z); a[7] = (short)f2bf(v1.w);
        int kb = c * 64 + ((lane >> 4) << 4);
        int kbs = kb ^ lsw;
        bf16x8 bf0 = *reinterpret_cast<const bf16x8*>((char*)Bs + ( 0 + (lane & 15)) * 512 + kbs);
        bf16x8 bf1 = *reinterpret_cast<const bf16x8*>((char*)Bs + (16 + (lane & 15)) * 512 + kbs);
        bf16x8 bf2 = *reinterpret_cast<const bf16x8*>((char*)Bs + (32 + (lane & 15)) * 512 + kbs);
        bf16x8 bf3 = *reinterpret_cast<const bf16x8*>((char*)Bs + (48 + (lane & 15)) * 512 + kbs);
        acc0 = __builtin_amdgcn_mfma_f32_16x16x32_bf16(a, bf0, acc0, 0, 0, 0);
        acc1 = __builtin_amdgcn_mfma_f32_16x16x32_bf16(a, bf1, acc1, 0, 0, 0);
        acc2 = __builtin_amdgcn_mfma_f32_16x16x32_bf16(a, bf2, acc2, 0, 0, 0);
        acc3 = __builtin_amdgcn_mfma_f32_16x16x32_bf16(a, bf3, acc3, 0, 0, 0);
    }
    #pragma unroll
    for (int reg = 0; reg < 4; ++reg) {
        int grow = rowbase + w * 16 + ((lane >> 4) << 2) + reg;
        if (grow < M) {
            float dv = dinv[grow];
            uchar* gp = &gb[(size_t)grow * H + (lane & 15)];
            gp[ 0] = f2fp8(acc0[reg] * dv);
            gp[16] = f2fp8(acc1[reg] * dv);
            gp[32] = f2fp8(acc2[reg] * dv);
            gp[48] = f2fp8(acc3[reg] * dv);
        }
    }
}

// ---- K6: agg (+wacc fixed-point), 32 quarter-waves/block -------------------
__global__ __launch_bounds__(512) void agg_kernel(const uchar* __restrict__ gb,
                                                  const int* __restrict__ bbase,
                                                  const int* __restrict__ bbase_s,
                                                  const int* __restrict__ qbase,
                                                  const int* __restrict__ sedge,
                                                  const int* __restrict__ srecs,
                                                  const float* __restrict__ dinv,
                                                  const float* __restrict__ b1,
                                                  float* __restrict__ svec, int N) {
    __shared__ float acc[BSZ][H];            // 32 KB
    __shared__ int   wli[BSZ];               // 512 B, fixed-point 2^24
    __shared__ float red[8][64];
    int t = threadIdx.x;
    int lane = t & 63;
    int w = t >> 6;                          // wave 0..7
    int qq = lane >> 4;                      // quarter-wave 0..3
    int cl4 = lane & 15;                     // covers cols [cl4*4, cl4*4+4)
    int b = blockIdx.x;
    float* af = &acc[0][0];
    for (int i = t; i < BSZ * H / 4; i += 512)
        reinterpret_cast<float4*>(af)[i] = make_float4(0.f, 0.f, 0.f, 0.f);
    if (t < BSZ) wli[t] = 0;
    __syncthreads();
    // ---- wacc phase: wli[src&127] += round(dinv[dst]*2^24)  (native ds_add)
    {
        int e0s = bbase_s[b], e1s = bbase_s[b + 1];
        for (int i = e0s + t; i < e1s; i += 512) {
            int p = srecs[i];                          // (dst<<7)|(src&127)
            int fx = (int)(dinv[(unsigned)p >> BSHIFT] * WSCALE + 0.5f);
            atomicAdd(&wli[p & (BSZ - 1)], fx);
        }
    }
    // ---- main gather phase
    int e0 = bbase[b];
    int m  = bbase[b + 1] - e0;
    int hw = (w << 2) | qq;                  // 0..31, owns dl&31==hw
    int qs = qbase[b * 32 + hw];
    int qe = (hw < 31) ? qbase[b * 32 + hw + 1] : m;
    const int* sp = sedge + e0;
    int c0 = cl4 << 2;
    int j = qs;
    for (; j + 3 < qe; j += 4) {
        int p0 = sp[j], p1 = sp[j + 1], p2 = sp[j + 2], p3 = sp[j + 3];
        uint u0 = *reinterpret_cast<const uint*>(gb + (((unsigned)p0 >> BSHIFT) << 6) + c0);
        uint u1 = *reinterpret_cast<const uint*>(gb + (((unsigned)p1 >> BSHIFT) << 6) + c0);
        uint u2 = *reinterpret_cast<const uint*>(gb + (((unsigned)p2 >> BSHIFT) << 6) + c0);
        uint u3 = *reinterpret_cast<const uint*>(gb + (((unsigned)p3 >> BSHIFT) << 6) + c0);
        f32x2 l0 = __builtin_amdgcn_cvt_pk_f32_fp8(u0, false);
        f32x2 h0 = __builtin_amdgcn_cvt_pk_f32_fp8(u0, true);
        float4* a0 = reinterpret_cast<float4*>(&acc[p0 & (BSZ - 1)][c0]);
        float4 r0 = *a0;
        r0.x += l0[0]; r0.y += l0[1]; r0.z += h0[0]; r0.w += h0[1];
        *a0 = r0;
        f32x2 l1 = __builtin_amdgcn_cvt_pk_f32_fp8(u1, false);
        f32x2 h1v = __builtin_amdgcn_cvt_pk_f32_fp8(u1, true);
        float4* a1 = reinterpret_cast<float4*>(&acc[p1 & (BSZ - 1)][c0]);
        float4 r1 = *a1;
        r1.x += l1[0]; r1.y += l1[1]; r1.z += h1v[0]; r1.w += h1v[1];
        *a1 = r1;
        f32x2 l2 = __builtin_amdgcn_cvt_pk_f32_fp8(u2, false);
        f32x2 h2 = __builtin_amdgcn_cvt_pk_f32_fp8(u2, true);
        float4* a2 = reinterpret_cast<float4*>(&acc[p2 & (BSZ - 1)][c0]);
        float4 r2 = *a2;
        r2.x += l2[0]; r2.y += l2[1]; r2.z += h2[0]; r2.w += h2[1];
        *a2 = r2;
        f32x2 l3 = __builtin_amdgcn_cvt_pk_f32_fp8(u3, false);
        f32x2 h3 = __builtin_amdgcn_cvt_pk_f32_fp8(u3, true);
        float4* a3 = reinterpret_cast<float4*>(&acc[p3 & (BSZ - 1)][c0]);
        float4 r3 = *a3;
        r3.x += l3[0]; r3.y += l3[1]; r3.z += h3[0]; r3.w += h3[1];
        *a3 = r3;
    }
    for (; j < qe; ++j) {
        int p = sp[j];
        uint u = *reinterpret_cast<const uint*>(gb + (((unsigned)p >> BSHIFT) << 6) + c0);
        f32x2 lo = __builtin_amdgcn_cvt_pk_f32_fp8(u, false);
        f32x2 hi = __builtin_amdgcn_cvt_pk_f32_fp8(u, true);
        float4* a = reinterpret_cast<float4*>(&acc[p & (BSZ - 1)][c0]);
        float4 r = *a;
        r.x += lo[0]; r.y += lo[1]; r.z += hi[0]; r.w += hi[1];
        *a = r;
    }
    __syncthreads();
    float bb = b1[lane];
    float racc = 0.f;
    #pragma unroll
    for (int r = 0; r < 16; ++r) {
        int dl = r * 8 + w;
        int n = (b << BSHIFT) + dl;
        if (n < N) {
            float dv = dinv[n];
            float a = acc[dl][lane] + fp82f(gb[(size_t)n * H + lane]);
            float h1 = fmaxf(dv * a + bb, 0.f);
            racc += (dv * ((float)wli[dl] * WINV + dv)) * h1;
        }
    }
    red[w][lane] = racc;
    __syncthreads();
    if (w == 0) {
        float vv = 0.f;
        #pragma unroll
        for (int k = 0; k < 8; ++k) vv += red[k][lane];
        atomicAdd(&svec[lane], vv);
    }
}

// ---- K7: final tiny head ---------------------------------------------------
__global__ void final_kernel(const float* __restrict__ svec,
                             const float* __restrict__ W2, const float* __restrict__ b2,
                             const float* __restrict__ Wl, const float* __restrict__ bl,
                             float* __restrict__ out, float invN) {
    __shared__ float pooled[64];
    __shared__ float sv[64];
    int t = threadIdx.x;
    sv[t] = svec[t];
    __syncthreads();
    float acc = 0.f;
    for (int k = 0; k < 64; ++k) acc += sv[k] * W2[k * 64 + t];
    pooled[t] = acc * invN + b2[t];
    __syncthreads();
    if (t < 10) {
        float a = 0.f;
        for (int j = 0; j < 64; ++j) a += pooled[j] * Wl[j * 10 + t];
        a += bl[t];
        out[t] = 1.f / (1.f + expf(-a));
    }
}

// ---------------------------------------------------------------------------
extern "C" void kernel_launch(void* const* d_in, const int* in_sizes, int n_in,
                              void* d_out, int out_size, void* d_ws, size_t ws_size,
                              hipStream_t stream) {
    const float* x   = (const float*)d_in[0];
    const int*   ei  = (const int*)d_in[1];
    const float* W1  = (const float*)d_in[2];
    const float* b1  = (const float*)d_in[3];
    const float* W2  = (const float*)d_in[4];
    const float* b2  = (const float*)d_in[5];
    const float* Wl  = (const float*)d_in[6];
    const float* bl  = (const float*)d_in[7];
    float* out = (float*)d_out;

    const int N = in_sizes[0] / F_IN;
    const int E = in_sizes[1] / 2;
    const int nbuck = (N + BSZ - 1) >> BSHIFT;       // 782 for N=100000
    const int NSB   = (N + 4095) >> 12;              // 25 src bins (32*NSB <= 1024)

    char* ws = (char*)d_ws;
    size_t off = 0;
    auto carve = [&](size_t bytes) -> char* {
        char* p = ws + off;
        off = (off + bytes + 255) & ~(size_t)255;
        return p;
    };
    int*   bcnt2    = (int*)  carve((size_t)2 * NBUCK_MAX * 4);  // [dst | src]
    int*   bcnt_d   = bcnt2;
    int*   bcnt_s   = bcnt2 + NBUCK_MAX;
    int*   bbase_d  = (int*)  carve((size_t)(NBUCK_MAX + 1) * 4);
    int*   bcur_d   = (int*)  carve((size_t)NBUCK_MAX * 4);
    int*   bbase_s  = (int*)  carve((size_t)(NBUCK_MAX + 1) * 4);
    int*   bcur_s   = (int*)  carve((size_t)NBUCK_MAX * 4);
    int*   qbase    = (int*)  carve((size_t)nbuck * 32 * 4);
    float* dinv     = (float*)carve((size_t)N * 4);
    float* svec     = (float*)carve(64 * 4);
    ushort* W1t     = (ushort*)carve((size_t)64 * 256 * 2);
    int*   sedge    = (int*)  carve((size_t)E * 4);
    int*   srecs    = (int*)  carve((size_t)E * 4);
    // overlay: recs_d (E*4) reused as gb (N*64*1) after build
    size_t ovl = (size_t)E * 4;
    size_t gsz = (size_t)N * H;
    char*  ovlp     = carve(ovl > gsz ? ovl : gsz);
    int*   recs_d   = (int*)ovlp;
    uchar* gb       = (uchar*)ovlp;
    (void)ws_size; (void)n_in; (void)out_size;

    hipMemsetAsync(bcnt2, 0, (size_t)2 * NBUCK_MAX * 4, stream);
    hipMemsetAsync(svec, 0, 64 * 4, stream);

    w1t_kernel<<<64, 256, 0, stream>>>(W1, W1t);
    hist_kernel<<<120, 256, 0, stream>>>(ei, bcnt_d, bcnt_s, E, nbuck);
    bscan_kernel<<<2, 1024, 0, stream>>>(bcnt_d, bcnt_s, bbase_d, bcur_d, bbase_s, bcur_s, nbuck, E);
    int gridP3 = (E + P3_CH - 1) / P3_CH;
    part2_kernel<<<gridP3, 512, 0, stream>>>(ei, bcur_d, bcur_s, recs_d, srecs, E);
    build_kernel<<<nbuck, 256, 0, stream>>>(recs_d, bbase_d, dinv, sedge, qbase, N, NSB);

    int gridM = (N + 63) / 64;
    gemm_mfma<<<gridM, 256, 0, stream>>>(x, W1t, dinv, gb, N);

    agg_kernel<<<nbuck, 512, 0, stream>>>(gb, bbase_d, bbase_s, qbase, sedge, srecs,
                                          dinv, b1, svec, N);

    final_kernel<<<1, 64, 0, stream>>>(svec, W2, b2, Wl, bl, out, 1.0f / (float)N);
}